// Round 12
// baseline (145.826 us; speedup 1.0000x reference)
//
#include <hip/hip_runtime.h>

// MGU forward, swapped-orientation split-f16 MFMA, per-tile-fused schedule.
// B=131072, TAU=20, HID=64. Block = 128 rows, 8 waves; wave owns 16 rows
// (r = lane&15), ALL 64 units. PRE^T = W * S, W in 2 f16 planes:
//   Whi = f16(W), Wlo = f16((W-Whi)*256); PRE = Ch + 2^-8*Cl.
// State enters as a single f16 plane. sigma keeps B-frag slots lane-local:
//   sigma(32s + 8q + i) = 16*(2s + (i>>2)) + 4q + (i&3)
//
// R12 pipe rebalance (R11 post-mortem: VALUBusy/MfmaUtil are 4-SIMD sums ->
// per-SIMD VALU ~14%, MFMA ~8%, LDS ~33%, but L1/global path ~66% busy at
// 24 KB/wave-step -- the tallest pipe):
//   LDS:    W-hi (16 reads) + aug (8 reads)  -> ~49% busy
//   GLOBAL: W-lo (16 reads, 16KB table in d_ws, L1-resident) -> ~44% busy
// If this doesn't move duration, the limiter is the serial step chain ->
// next lever is 32-row waves at launch_bounds(512,1).
//
// CRITICAL: empirical VGPR cap = 256 / launch_bounds_arg2 (W=2 -> 128;
// W=3 -> 84; W=4 -> 64; verified R1/R6/R7). Peak live ~105-110 => W=2.
//
// Fragment maps (m89-verified, R5-R11 validated end-to-end):
//   A: lane L holds A[m=L&15][k=(L>>4)*8+i]; B: lane L holds B[k=(L>>4)*8+i][n=L&15]
//   C/D: lane L reg i holds D[m=(L>>4)*4+i][n=L&15]

constexpr int BATCH = 131072;
constexpr int TAU   = 20;
constexpr int HID   = 64;
constexpr int FAN   = 65;
constexpr int NT    = 512;
constexpr int ROWS  = 128;

typedef float    f32x4 __attribute__((ext_vector_type(4)));
typedef _Float16 f16x8 __attribute__((ext_vector_type(8)));
typedef unsigned u32x4 __attribute__((ext_vector_type(4)));

static constexpr float LOG2E  = 1.4426950408889634f;
static constexpr float RCP256 = 0.00390625f;

static __device__ __forceinline__ unsigned pkrtz(float a, float b) {
    return __builtin_bit_cast(unsigned, __builtin_amdgcn_cvt_pkrtz(a, b));
}
#define PK8(a0,a1,a2,a3,a4,a5,a6,a7) \
    __builtin_bit_cast(f16x8, (u32x4){pkrtz(a0,a1), pkrtz(a2,a3), \
                                      pkrtz(a4,a5), pkrtz(a6,a7)})

#define MFMAH(A, B, C) __builtin_amdgcn_mfma_f32_16x16x32_f16((A), (B), (C), 0, 0, 0)

// chunk base (in halfs) for (g, T, s): 16 chunks x 512
#define HOFF(g, T, s) ((((g) * 8) + ((T) * 2) + (s)) * 512)

// ---------------- pre-kernel: lo-plane + aug table + zero pad in d_ws -------
// ws layout (halfs): [0..8191] lo chunks HOFF(g,T,s)+L*8+i
//                    [8192..9215] aug chunks (g*4+T)*128 + m*8 + i
//                    [9216..10239] zeros (q!=0 aug reads land here)
__global__ void mgu_stage(const float* __restrict__ Wf, const float* __restrict__ bfv,
                          const float* __restrict__ Wc, const float* __restrict__ bcv,
                          _Float16* __restrict__ ws)
{
    const int tid = threadIdx.x;
    for (int idx = tid; idx < 8192; idx += 256) {
        const int i = idx & 7, Li = (idx >> 3) & 63, s = (idx >> 9) & 1,
                  T = (idx >> 10) & 3, g = (idx >> 12) & 1;
        const int u = 16 * (2 * s + (i >> 2)) + 4 * (Li >> 4) + (i & 3); // sigma
        const float* Wg = g ? Wc : Wf;
        const float sc = g ? (2.0f * LOG2E) : (-LOG2E);
        const float wv = sc * Wg[(16 * T + (Li & 15)) * FAN + 1 + u];
        const _Float16 hi = (_Float16)wv;
        ws[HOFF(g, T, s) + (idx & 511)] = (_Float16)((wv - (float)hi) * 256.0f);
    }
    if (tid < 128) {
        const int m = tid & 15, T = (tid >> 4) & 3, g = tid >> 6;
        const float* Wg = g ? Wc : Wf;
        const float* bg = g ? bcv : bfv;
        const float sc = g ? (2.0f * LOG2E) : (-LOG2E);
        const float fx = sc * Wg[(16 * T + m) * FAN];
        const float fb = sc * bg[16 * T + m];
        const _Float16 fxh = (_Float16)fx;
        const _Float16 fbh = (_Float16)fb;
        _Float16* c = &ws[8192 + (g * 4 + T) * 128 + m * 8];
        c[0] = fxh;
        c[1] = (_Float16)((fx - (float)fxh) * 256.0f);
        c[2] = fxh;
        c[3] = fbh;
        c[4] = (_Float16)((fb - (float)fbh) * 256.0f);
        c[5] = (_Float16)0.0f; c[6] = (_Float16)0.0f; c[7] = (_Float16)0.0f;
    }
    for (int idx = tid; idx < 1024; idx += 256) ws[9216 + idx] = (_Float16)0.0f;
}

// ---------------- main kernel ----------------

#define LD_HI(g, T, s)  (*(const f16x8*)&sWhi[HOFF(g, T, s) + Lx8])
#define LD_LO(g, T, s)  (*(const f16x8*)(wsLo + HOFF(g, T, s) + Lx8))
#define LD_AUG(g, T)    (*(const f16x8*)&sAug[(g * 4 + T) * 128 + augSel])

// F = 1/(1 + exp2(Ch + 2^-8 Cl)); paired rcp
#define SIGF4(F, CH, CL) { \
    const float e0_ = __builtin_amdgcn_exp2f(fmaf(RCP256, CL[0], CH[0])); \
    const float e1_ = __builtin_amdgcn_exp2f(fmaf(RCP256, CL[1], CH[1])); \
    const float e2_ = __builtin_amdgcn_exp2f(fmaf(RCP256, CL[2], CH[2])); \
    const float e3_ = __builtin_amdgcn_exp2f(fmaf(RCP256, CL[3], CH[3])); \
    const float d0_ = 1.0f + e0_, d1_ = 1.0f + e1_; \
    const float d2_ = 1.0f + e2_, d3_ = 1.0f + e3_; \
    const float i01_ = __builtin_amdgcn_rcpf(d0_ * d1_); \
    const float i23_ = __builtin_amdgcn_rcpf(d2_ * d3_); \
    F[0] = d1_ * i01_; F[1] = d0_ * i01_; \
    F[2] = d3_ * i23_; F[3] = d2_ * i23_; }

// tanh = 1 - 2/(1 + exp2(.)); S = S + F * (tanh - S)
#define UPDF4(S, F, CH, CL) { \
    const float e0_ = __builtin_amdgcn_exp2f(fmaf(RCP256, CL[0], CH[0])); \
    const float e1_ = __builtin_amdgcn_exp2f(fmaf(RCP256, CL[1], CH[1])); \
    const float e2_ = __builtin_amdgcn_exp2f(fmaf(RCP256, CL[2], CH[2])); \
    const float e3_ = __builtin_amdgcn_exp2f(fmaf(RCP256, CL[3], CH[3])); \
    const float d0_ = 1.0f + e0_, d1_ = 1.0f + e1_; \
    const float d2_ = 1.0f + e2_, d3_ = 1.0f + e3_; \
    const float j01_ = -2.0f * __builtin_amdgcn_rcpf(d0_ * d1_); \
    const float j23_ = -2.0f * __builtin_amdgcn_rcpf(d2_ * d3_); \
    const float t0_ = fmaf(d1_, j01_, 1.0f); \
    const float t1_ = fmaf(d0_, j01_, 1.0f); \
    const float t2_ = fmaf(d3_, j23_, 1.0f); \
    const float t3_ = fmaf(d2_, j23_, 1.0f); \
    S[0] = fmaf(F[0], t0_ - S[0], S[0]); S[1] = fmaf(F[1], t1_ - S[1], S[1]); \
    S[2] = fmaf(F[2], t2_ - S[2], S[2]); S[3] = fmaf(F[3], t3_ - S[3], S[3]); }

// one forget-gate tile: aug + 2 ksteps (hi+lo) + sigmoid, C-regs local
#define FTILE(T, FT) { \
    f32x4 ch_ = MFMAH(LD_AUG(0, T), augB, z4); \
    f32x4 cl_ = z4; \
    ch_ = MFMAH(LD_HI(0, T, 0), BS0, ch_); cl_ = MFMAH(LD_LO(0, T, 0), BS0, cl_); \
    ch_ = MFMAH(LD_HI(0, T, 1), BS1, ch_); cl_ = MFMAH(LD_LO(0, T, 1), BS1, cl_); \
    SIGF4(FT, ch_, cl_) }

__global__ __launch_bounds__(NT, 2) void mgu_fwd(
    const float* __restrict__ x,    // [B, TAU]
    const float* __restrict__ h0,   // [B, HID]
    const float* __restrict__ Wf,   // [HID, FAN]
    const float* __restrict__ bfv,  // [HID]
    const float* __restrict__ Wc,   // [HID, FAN]
    const float* __restrict__ bcv,  // [HID]
    const float* __restrict__ Wo,   // [1, HID]
    const float* __restrict__ bov,  // [1]
    const _Float16* __restrict__ ws,
    float* __restrict__ out)        // [B, 1]
{
    __shared__ _Float16 sWhi[8192];   // hi planes, 16 chunks x 512
    __shared__ _Float16 sAug[2048];   // aug chunks + zero pad (from ws)
    __shared__ float sX[ROWS * TAU];
    __shared__ float sWo[HID];

    const int tid = threadIdx.x;
    const long rb0 = (long)blockIdx.x * ROWS;

    // ---- one-time: hi planes -> LDS (sigma order, exp2-domain scale)
    for (int idx = tid; idx < 8192; idx += NT) {
        const int i = idx & 7, Li = (idx >> 3) & 63, s = (idx >> 9) & 1,
                  T = (idx >> 10) & 3, g = (idx >> 12) & 1;
        const int u = 16 * (2 * s + (i >> 2)) + 4 * (Li >> 4) + (i & 3); // sigma
        const float* Wg = g ? Wc : Wf;
        const float sc = g ? (2.0f * LOG2E) : (-LOG2E);
        sWhi[HOFF(g, T, s) + (idx & 511)] =
            (_Float16)(sc * Wg[(16 * T + (Li & 15)) * FAN + 1 + u]);
    }
    // ---- one-time: aug chunks (incl. zero pad) -> LDS
    for (int idx = tid; idx < 2048; idx += NT) sAug[idx] = ws[8192 + idx];
    for (int i2 = tid; i2 < ROWS * TAU; i2 += NT) sX[i2] = x[rb0 * TAU + i2];
    if (tid < HID) sWo[tid] = Wo[tid];
    __syncthreads();

    const int w = tid >> 6, L = tid & 63, q = L >> 4, r = L & 15;
    const int lr = w * 16 + r;
    const long gr = rb0 + lr;
    const int Lx8 = L * 8;

    const _Float16* wsLo = ws;
    const int augSel = (q == 0) ? (r * 8) : 1024;   // q>0 -> zero pad region

    const f32x4 z4 = {0.f, 0.f, 0.f, 0.f};

    // ---- state: S_T[i] = H[16T + 4q + i][r]
    f32x4 S0 = *(const f32x4*)&h0[gr * HID +  0 + 4 * q];
    f32x4 S1 = *(const f32x4*)&h0[gr * HID + 16 + 4 * q];
    f32x4 S2 = *(const f32x4*)&h0[gr * HID + 32 + 4 * q];
    f32x4 S3 = *(const f32x4*)&h0[gr * HID + 48 + 4 * q];

    #pragma unroll 1
    for (int t = 0; t < TAU; ++t) {
        // ---- aug B-frag: [xh, xh*2^-8, xl, 1, 2^-8, 0,0,0] (q==0 lanes)
        const float xt = sX[lr * TAU + t];
        f16x8 augB;
        {
            const _Float16 xh = (_Float16)xt;
            const float xhf = (float)xh;
            unsigned d0 = pkrtz(xhf, xhf * RCP256);
            unsigned d1 = pkrtz(xt - xhf, 1.0f);
            unsigned d2 = pkrtz(RCP256, 0.0f);
            if (q != 0) { d0 = 0; d1 = 0; d2 = 0; }
            augB = __builtin_bit_cast(f16x8, (u32x4){d0, d1, d2, 0u});
        }

        // ---- B-frags of S (single f16 plane, pkrtz)
        const f16x8 BS0 = PK8(S0[0],S0[1],S0[2],S0[3], S1[0],S1[1],S1[2],S1[3]);
        const f16x8 BS1 = PK8(S2[0],S2[1],S2[2],S2[3], S3[0],S3[1],S3[2],S3[3]);

        // ---- candidate-gate aug MFMAs: depend only on x -> issue first
        f32x4 CcH0 = MFMAH(LD_AUG(1, 0), augB, z4);
        f32x4 CcH1 = MFMAH(LD_AUG(1, 1), augB, z4);
        f32x4 CcH2 = MFMAH(LD_AUG(1, 2), augB, z4);
        f32x4 CcH3 = MFMAH(LD_AUG(1, 3), augB, z4);
        f32x4 CcL0 = z4, CcL1 = z4, CcL2 = z4, CcL3 = z4;

        // ---- F tiles 0,1 (their SIGF overlaps C-aug / later MFMAs)
        f32x4 F0, F1, F2, F3;
        FTILE(0, F0)
        FTILE(1, F1)

        // ---- BG0 (units 0..31) ready -> C-gate kstep 0
        const f32x4 G0 = F0 * S0, G1 = F1 * S1;
        const f16x8 BG0 = PK8(G0[0],G0[1],G0[2],G0[3], G1[0],G1[1],G1[2],G1[3]);
        __builtin_amdgcn_s_setprio(1);
        CcH0 = MFMAH(LD_HI(1, 0, 0), BG0, CcH0); CcL0 = MFMAH(LD_LO(1, 0, 0), BG0, CcL0);
        CcH1 = MFMAH(LD_HI(1, 1, 0), BG0, CcH1); CcL1 = MFMAH(LD_LO(1, 1, 0), BG0, CcL1);
        CcH2 = MFMAH(LD_HI(1, 2, 0), BG0, CcH2); CcL2 = MFMAH(LD_LO(1, 2, 0), BG0, CcL2);
        CcH3 = MFMAH(LD_HI(1, 3, 0), BG0, CcH3); CcL3 = MFMAH(LD_LO(1, 3, 0), BG0, CcL3);
        __builtin_amdgcn_s_setprio(0);

        // ---- F tiles 2,3 (SIGF overlaps kstep-0 MFMAs above)
        FTILE(2, F2)
        FTILE(3, F3)

        // ---- BG1 (units 32..63) -> C-gate kstep 1
        const f32x4 G2 = F2 * S2, G3 = F3 * S3;
        const f16x8 BG1 = PK8(G2[0],G2[1],G2[2],G2[3], G3[0],G3[1],G3[2],G3[3]);
        __builtin_amdgcn_s_setprio(1);
        CcH0 = MFMAH(LD_HI(1, 0, 1), BG1, CcH0); CcL0 = MFMAH(LD_LO(1, 0, 1), BG1, CcL0);
        CcH1 = MFMAH(LD_HI(1, 1, 1), BG1, CcH1); CcL1 = MFMAH(LD_LO(1, 1, 1), BG1, CcL1);
        CcH2 = MFMAH(LD_HI(1, 2, 1), BG1, CcH2); CcL2 = MFMAH(LD_LO(1, 2, 1), BG1, CcL2);
        CcH3 = MFMAH(LD_HI(1, 3, 1), BG1, CcH3); CcL3 = MFMAH(LD_LO(1, 3, 1), BG1, CcL3);
        __builtin_amdgcn_s_setprio(0);

        // ---- update: S = S + F * (tanh - S)
        UPDF4(S0, F0, CcH0, CcL0)
        UPDF4(S1, F1, CcH1, CcL1)
        UPDF4(S2, F2, CcH2, CcL2)
        UPDF4(S3, F3, CcH3, CcL3)
    }

    // ---- output: out[r] = bo + Wo . H ; reduce over the 4 q-groups
    const f32x4 wo0 = *(const f32x4*)&sWo[ 0 + 4 * q];
    const f32x4 wo1 = *(const f32x4*)&sWo[16 + 4 * q];
    const f32x4 wo2 = *(const f32x4*)&sWo[32 + 4 * q];
    const f32x4 wo3 = *(const f32x4*)&sWo[48 + 4 * q];
    float acc = 0.0f;
    acc = fmaf(wo0[0], S0[0], acc); acc = fmaf(wo0[1], S0[1], acc);
    acc = fmaf(wo0[2], S0[2], acc); acc = fmaf(wo0[3], S0[3], acc);
    acc = fmaf(wo1[0], S1[0], acc); acc = fmaf(wo1[1], S1[1], acc);
    acc = fmaf(wo1[2], S1[2], acc); acc = fmaf(wo1[3], S1[3], acc);
    acc = fmaf(wo2[0], S2[0], acc); acc = fmaf(wo2[1], S2[1], acc);
    acc = fmaf(wo2[2], S2[2], acc); acc = fmaf(wo2[3], S2[3], acc);
    acc = fmaf(wo3[0], S3[0], acc); acc = fmaf(wo3[1], S3[1], acc);
    acc = fmaf(wo3[2], S3[2], acc); acc = fmaf(wo3[3], S3[3], acc);
    acc += __shfl_xor(acc, 16, 64);
    acc += __shfl_xor(acc, 32, 64);
    if (q == 0) out[gr] = acc + bov[0];
}

extern "C" void kernel_launch(void* const* d_in, const int* in_sizes, int n_in,
                              void* d_out, int out_size, void* d_ws, size_t ws_size,
                              hipStream_t stream) {
    const float* x  = (const float*)d_in[0];
    const float* h0 = (const float*)d_in[1];
    const float* Wf = (const float*)d_in[2];
    const float* bf = (const float*)d_in[3];
    const float* Wc = (const float*)d_in[4];
    const float* bc = (const float*)d_in[5];
    const float* Wo = (const float*)d_in[6];
    const float* bo = (const float*)d_in[7];
    float* out = (float*)d_out;
    _Float16* ws = (_Float16*)d_ws;   // needs 10240 halfs = 20.5 KB

    hipLaunchKernelGGL(mgu_stage, dim3(1), dim3(256), 0, stream,
                       Wf, bf, Wc, bc, ws);
    hipLaunchKernelGGL(mgu_fwd, dim3(BATCH / ROWS), dim3(NT), 0, stream,
                       x, h0, Wf, bf, Wc, bc, Wo, bo, (const _Float16*)ws, out);
}

// Round 13
// 101.506 us; speedup vs baseline: 1.4366x; 1.4366x over previous
//
#include <hip/hip_runtime.h>

// MGU forward, swapped-orientation f16 MFMA, hi-plane-only + 6-waves/SIMD.
// B=131072, TAU=20, HID=64. Block = 64 rows, 4 waves; wave owns 16 rows
// (r = lane&15), ALL 64 units. PRE^T = W * S with W in ONE f16 plane
// (R13: both lo planes dropped -- error analysis: f16 weight rel err
// ~1.4e-4 rms -> per-step pre err ~6e-5, contractive recurrence -> absmax
// ~4-9e-4 < 1.245e-3 threshold; fallback if exceeded: restore candidate-lo
// at launch_bounds W=2). Aug (bias + x) stays FULL split precision (free).
// sigma keeps B-frag slots lane-local (zero cross-lane ops, zero LDS writes
// in the recurrence):  sigma(32s + 8q + i) = 16*(2s + (i>>2)) + 4q + (i&3)
//
// R13 rationale (R11+R12 null results): no pipe saturated (VALU ~55%, LDS
// ~53%, L1 ~47%, MFMA ~9% per-SIMD) -> latency-bound at 4 waves/SIMD. The
// VGPR law (cap = 256/launch_bounds_arg2; verified R1/R6/R7/R8) allows only
// 128 (4 waves) or 85 (6 waves). Dropping lo planes shrinks live state to
// ~76 regs -> W=3 fits -> 24 waves/CU (+50% TLP). MFMA 40->24/step, zero
// in-loop global traffic, quad-rcp trims trans 48->40/step.
//
// Fragment maps (m89-verified, R5-R12 validated end-to-end):
//   A: lane L holds A[m=L&15][k=(L>>4)*8+i]; B: lane L holds B[k=(L>>4)*8+i][n=L&15]
//   C/D: lane L reg i holds D[m=(L>>4)*4+i][n=L&15]

constexpr int BATCH = 131072;
constexpr int TAU   = 20;
constexpr int HID   = 64;
constexpr int FAN   = 65;
constexpr int NT    = 256;
constexpr int ROWS  = 64;

typedef float    f32x4 __attribute__((ext_vector_type(4)));
typedef _Float16 f16x8 __attribute__((ext_vector_type(8)));
typedef unsigned u32x4 __attribute__((ext_vector_type(4)));

static constexpr float LOG2E  = 1.4426950408889634f;
static constexpr float RCP256 = 0.00390625f;

static __device__ __forceinline__ unsigned pkrtz(float a, float b) {
    return __builtin_bit_cast(unsigned, __builtin_amdgcn_cvt_pkrtz(a, b));
}
#define PK8(a0,a1,a2,a3,a4,a5,a6,a7) \
    __builtin_bit_cast(f16x8, (u32x4){pkrtz(a0,a1), pkrtz(a2,a3), \
                                      pkrtz(a4,a5), pkrtz(a6,a7)})

#define MFMAH(A, B, C) __builtin_amdgcn_mfma_f32_16x16x32_f16((A), (B), (C), 0, 0, 0)

// hi-plane chunk base (halfs) for (g, T, s): 16 chunks x 512
#define HOFF(g, T, s) ((((g) * 8) + ((T) * 2) + (s)) * 512)

#define LD_HI(g, T, s)  (*(const f16x8*)&sWhi[HOFF(g, T, s) + Lx8])
#define LD_AUG(g, T)    (*(const f16x8*)&sAug[augMul * ((g) * 4 + (T)) + augSel])

// F = 1/(1 + exp2(C)); quad rcp (1 v_rcp per 4 elements)
#define SIGF4(F, C) { \
    const float e0_ = __builtin_amdgcn_exp2f(C[0]); \
    const float e1_ = __builtin_amdgcn_exp2f(C[1]); \
    const float e2_ = __builtin_amdgcn_exp2f(C[2]); \
    const float e3_ = __builtin_amdgcn_exp2f(C[3]); \
    const float d0_ = 1.0f + e0_, d1_ = 1.0f + e1_; \
    const float d2_ = 1.0f + e2_, d3_ = 1.0f + e3_; \
    const float d01_ = d0_ * d1_, d23_ = d2_ * d3_; \
    const float ii_  = __builtin_amdgcn_rcpf(d01_ * d23_); \
    const float i01_ = ii_ * d23_, i23_ = ii_ * d01_; \
    F[0] = d1_ * i01_; F[1] = d0_ * i01_; \
    F[2] = d3_ * i23_; F[3] = d2_ * i23_; }

// tanh = 1 - 2/(1 + exp2(C)); S = S + F * (tanh - S); quad rcp
#define UPDF4(S, F, C) { \
    const float e0_ = __builtin_amdgcn_exp2f(C[0]); \
    const float e1_ = __builtin_amdgcn_exp2f(C[1]); \
    const float e2_ = __builtin_amdgcn_exp2f(C[2]); \
    const float e3_ = __builtin_amdgcn_exp2f(C[3]); \
    const float d0_ = 1.0f + e0_, d1_ = 1.0f + e1_; \
    const float d2_ = 1.0f + e2_, d3_ = 1.0f + e3_; \
    const float d01_ = d0_ * d1_, d23_ = d2_ * d3_; \
    const float ii_  = __builtin_amdgcn_rcpf(d01_ * d23_); \
    const float j01_ = -2.0f * (ii_ * d23_), j23_ = -2.0f * (ii_ * d01_); \
    const float t0_ = fmaf(d1_, j01_, 1.0f); \
    const float t1_ = fmaf(d0_, j01_, 1.0f); \
    const float t2_ = fmaf(d3_, j23_, 1.0f); \
    const float t3_ = fmaf(d2_, j23_, 1.0f); \
    S[0] = fmaf(F[0], t0_ - S[0], S[0]); S[1] = fmaf(F[1], t1_ - S[1], S[1]); \
    S[2] = fmaf(F[2], t2_ - S[2], S[2]); S[3] = fmaf(F[3], t3_ - S[3], S[3]); }

// one forget-gate tile: aug + 2 hi ksteps + sigmoid (C-reg local)
#define FTILE(T, FT) { \
    f32x4 ch_ = MFMAH(LD_AUG(0, T), augB, z4); \
    ch_ = MFMAH(LD_HI(0, T, 0), BS0, ch_); \
    ch_ = MFMAH(LD_HI(0, T, 1), BS1, ch_); \
    SIGF4(FT, ch_) }

__global__ __launch_bounds__(NT, 3) void mgu_fwd(
    const float* __restrict__ x,    // [B, TAU]
    const float* __restrict__ h0,   // [B, HID]
    const float* __restrict__ Wf,   // [HID, FAN]
    const float* __restrict__ bfv,  // [HID]
    const float* __restrict__ Wc,   // [HID, FAN]
    const float* __restrict__ bcv,  // [HID]
    const float* __restrict__ Wo,   // [1, HID]
    const float* __restrict__ bov,  // [1]
    float* __restrict__ out)        // [B, 1]
{
    __shared__ _Float16 sWhi[8192];   // hi planes, 16 chunks x 512
    __shared__ _Float16 sAug[1032];   // aug chunks (g*4+T)*128+m*8; [1024..1031]=0
    __shared__ float sX[ROWS * TAU];
    __shared__ float sWo[HID];

    const int tid = threadIdx.x;
    const long rb0 = (long)blockIdx.x * ROWS;

    // ---- one-time: hi planes -> LDS (sigma order, exp2-domain scale)
    for (int idx = tid; idx < 8192; idx += NT) {
        const int i = idx & 7, Li = (idx >> 3) & 63, s = (idx >> 9) & 1,
                  T = (idx >> 10) & 3, g = (idx >> 12) & 1;
        const int u = 16 * (2 * s + (i >> 2)) + 4 * (Li >> 4) + (i & 3); // sigma
        const float* Wg = g ? Wc : Wf;
        const float sc = g ? (2.0f * LOG2E) : (-LOG2E);
        sWhi[HOFF(g, T, s) + (idx & 511)] =
            (_Float16)(sc * Wg[(16 * T + (Li & 15)) * FAN + 1 + u]);
    }
    // ---- one-time: aug chunks (bias + x-column, full split precision)
    if (tid < 128) {
        const int m = tid & 15, T = (tid >> 4) & 3, g = tid >> 6;
        const float* Wg = g ? Wc : Wf;
        const float* bg = g ? bcv : bfv;
        const float sc = g ? (2.0f * LOG2E) : (-LOG2E);
        const float fx = sc * Wg[(16 * T + m) * FAN];
        const float fb = sc * bg[16 * T + m];
        const _Float16 fxh = (_Float16)fx;
        const _Float16 fbh = (_Float16)fb;
        _Float16* c = &sAug[(g * 4 + T) * 128 + m * 8];
        c[0] = fxh;
        c[1] = (_Float16)((fx - (float)fxh) * 256.0f);
        c[2] = fxh;
        c[3] = fbh;
        c[4] = (_Float16)((fb - (float)fbh) * 256.0f);
        c[5] = (_Float16)0.0f; c[6] = (_Float16)0.0f; c[7] = (_Float16)0.0f;
    }
    if (tid < 8) sAug[1024 + tid] = (_Float16)0.0f;
    for (int i2 = tid; i2 < ROWS * TAU; i2 += NT) sX[i2] = x[rb0 * TAU + i2];
    if (tid < HID) sWo[tid] = Wo[tid];
    __syncthreads();

    const int w = tid >> 6, L = tid & 63, q = L >> 4, r = L & 15;
    const int lr = w * 16 + r;
    const long gr = rb0 + lr;
    const int Lx8 = L * 8;

    const int augMul = (q == 0) ? 128 : 0;
    const int augSel = (q == 0) ? (r * 8) : 1024;   // q>0 -> zero chunk

    const f32x4 z4 = {0.f, 0.f, 0.f, 0.f};

    // ---- state: S_T[i] = H[16T + 4q + i][r]
    f32x4 S0 = *(const f32x4*)&h0[gr * HID +  0 + 4 * q];
    f32x4 S1 = *(const f32x4*)&h0[gr * HID + 16 + 4 * q];
    f32x4 S2 = *(const f32x4*)&h0[gr * HID + 32 + 4 * q];
    f32x4 S3 = *(const f32x4*)&h0[gr * HID + 48 + 4 * q];

    #pragma unroll 1
    for (int t = 0; t < TAU; ++t) {
        // ---- aug B-frag: [xh, xh*2^-8, xl, 1, 2^-8, 0,0,0] (q==0 lanes)
        const float xt = sX[lr * TAU + t];
        f16x8 augB;
        {
            const _Float16 xh = (_Float16)xt;
            const float xhf = (float)xh;
            unsigned d0 = pkrtz(xhf, xhf * RCP256);
            unsigned d1 = pkrtz(xt - xhf, 1.0f);
            unsigned d2 = pkrtz(RCP256, 0.0f);
            if (q != 0) { d0 = 0; d1 = 0; d2 = 0; }
            augB = __builtin_bit_cast(f16x8, (u32x4){d0, d1, d2, 0u});
        }

        // ---- B-frags of S (single f16 plane, pkrtz)
        const f16x8 BS0 = PK8(S0[0],S0[1],S0[2],S0[3], S1[0],S1[1],S1[2],S1[3]);
        const f16x8 BS1 = PK8(S2[0],S2[1],S2[2],S2[3], S3[0],S3[1],S3[2],S3[3]);

        // ---- candidate-gate aug MFMAs: depend only on x -> issue first
        f32x4 CcH0 = MFMAH(LD_AUG(1, 0), augB, z4);
        f32x4 CcH1 = MFMAH(LD_AUG(1, 1), augB, z4);
        f32x4 CcH2 = MFMAH(LD_AUG(1, 2), augB, z4);
        f32x4 CcH3 = MFMAH(LD_AUG(1, 3), augB, z4);

        // ---- F tiles 0,1 (SIGF overlaps candidate MFMAs)
        f32x4 F0, F1, F2, F3;
        FTILE(0, F0)
        FTILE(1, F1)

        // ---- BG0 (units 0..31) -> candidate kstep 0
        const f32x4 G0 = F0 * S0, G1 = F1 * S1;
        const f16x8 BG0 = PK8(G0[0],G0[1],G0[2],G0[3], G1[0],G1[1],G1[2],G1[3]);
        __builtin_amdgcn_s_setprio(1);
        CcH0 = MFMAH(LD_HI(1, 0, 0), BG0, CcH0);
        CcH1 = MFMAH(LD_HI(1, 1, 0), BG0, CcH1);
        CcH2 = MFMAH(LD_HI(1, 2, 0), BG0, CcH2);
        CcH3 = MFMAH(LD_HI(1, 3, 0), BG0, CcH3);
        __builtin_amdgcn_s_setprio(0);

        // ---- F tiles 2,3 (SIGF overlaps kstep-0 MFMAs)
        FTILE(2, F2)
        FTILE(3, F3)

        // ---- BG1 (units 32..63) -> candidate kstep 1
        const f32x4 G2 = F2 * S2, G3 = F3 * S3;
        const f16x8 BG1 = PK8(G2[0],G2[1],G2[2],G2[3], G3[0],G3[1],G3[2],G3[3]);
        __builtin_amdgcn_s_setprio(1);
        CcH0 = MFMAH(LD_HI(1, 0, 1), BG1, CcH0);
        CcH1 = MFMAH(LD_HI(1, 1, 1), BG1, CcH1);
        CcH2 = MFMAH(LD_HI(1, 2, 1), BG1, CcH2);
        CcH3 = MFMAH(LD_HI(1, 3, 1), BG1, CcH3);
        __builtin_amdgcn_s_setprio(0);

        // ---- update: S = S + F * (tanh - S)
        UPDF4(S0, F0, CcH0)
        UPDF4(S1, F1, CcH1)
        UPDF4(S2, F2, CcH2)
        UPDF4(S3, F3, CcH3)
    }

    // ---- output: out[r] = bo + Wo . H ; reduce over the 4 q-groups
    const f32x4 wo0 = *(const f32x4*)&sWo[ 0 + 4 * q];
    const f32x4 wo1 = *(const f32x4*)&sWo[16 + 4 * q];
    const f32x4 wo2 = *(const f32x4*)&sWo[32 + 4 * q];
    const f32x4 wo3 = *(const f32x4*)&sWo[48 + 4 * q];
    float acc = 0.0f;
    acc = fmaf(wo0[0], S0[0], acc); acc = fmaf(wo0[1], S0[1], acc);
    acc = fmaf(wo0[2], S0[2], acc); acc = fmaf(wo0[3], S0[3], acc);
    acc = fmaf(wo1[0], S1[0], acc); acc = fmaf(wo1[1], S1[1], acc);
    acc = fmaf(wo1[2], S1[2], acc); acc = fmaf(wo1[3], S1[3], acc);
    acc = fmaf(wo2[0], S2[0], acc); acc = fmaf(wo2[1], S2[1], acc);
    acc = fmaf(wo2[2], S2[2], acc); acc = fmaf(wo2[3], S2[3], acc);
    acc = fmaf(wo3[0], S3[0], acc); acc = fmaf(wo3[1], S3[1], acc);
    acc = fmaf(wo3[2], S3[2], acc); acc = fmaf(wo3[3], S3[3], acc);
    acc += __shfl_xor(acc, 16, 64);
    acc += __shfl_xor(acc, 32, 64);
    if (q == 0) out[gr] = acc + bov[0];
}

extern "C" void kernel_launch(void* const* d_in, const int* in_sizes, int n_in,
                              void* d_out, int out_size, void* d_ws, size_t ws_size,
                              hipStream_t stream) {
    const float* x  = (const float*)d_in[0];
    const float* h0 = (const float*)d_in[1];
    const float* Wf = (const float*)d_in[2];
    const float* bf = (const float*)d_in[3];
    const float* Wc = (const float*)d_in[4];
    const float* bc = (const float*)d_in[5];
    const float* Wo = (const float*)d_in[6];
    const float* bo = (const float*)d_in[7];
    float* out = (float*)d_out;

    hipLaunchKernelGGL(mgu_fwd, dim3(BATCH / ROWS), dim3(NT), 0, stream,
                       x, h0, Wf, bf, Wc, bc, Wo, bo, out);
}

// Round 14
// 101.371 us; speedup vs baseline: 1.4385x; 1.0013x over previous
//
#include <hip/hip_runtime.h>

// MGU forward, swapped-orientation f16 MFMA, 32x32x16 shape. B=131072, TAU=20,
// HID=64. Block = 128 rows, 4 waves; wave owns 32 rows (row = lane&31), ALL 64
// units. PRE^T = W * S, W in ONE f16 plane (R13-validated: absmax unchanged).
// Per gate: 2 unit-tiles (M) x 4 ksteps (s) of v_mfma_f32_32x32x16_f16.
//
// R14 rationale (R13 PMC): LDS pipe was the tallest (24 b128/step/wave x 12cyc
// = ~77us of 115). 32x32 amortizes each W-fragment read over 32 rows ->
// 20 reads per 32-row step (-58% per row). Cost: S/F/Cc = 3 x f32x16 = 96 VGPR
// -> W=2 (cap 128), 4 waves/SIMD. NT=256/ROWS=128 -> grid 1024 = exactly
// 4 blocks/CU, ONE clean round, no tail (R13 had 8-on-6 with a 33% tail).
//
// sigma column permutation (lane-locality of B-frags, re-derived for 32x32):
//   k_global = 16s + k_local, k_local = 8h + i (h = lane>>5, i = elem 0..7)
//   sigma: u = (i&3) + 4h + 8s + 32*(i>>2)
// => B-frag slot i of kstep s at lane (h, row) = S[tile M=i>>2][reg 4s+(i&3)]
//    which is this lane's own D/epilogue register (zero cross-lane, zero LDS
//    writes in the recurrence).
// Fragment maps: A: lane L holds A[m=L&31][k=(L>>5)*8+i]; B: B[k=(L>>5)*8+i][n=L&31];
// C/D: col=lane&31, row=(reg&3)+8*(reg>>2)+4*(lane>>5)  [m101-verified 32x32].
// Aug (bias + x) full split precision, rank-5, zero on h=1 lanes.
//
// CRITICAL: empirical VGPR cap = 256 / launch_bounds_arg2 (verified R1/R6/R7).
// Peak live ~120 => W=2 REQUIRED. Spill indicator: FETCH >> 2.2e4 KB.

constexpr int BATCH = 131072;
constexpr int TAU   = 20;
constexpr int HID   = 64;
constexpr int FAN   = 65;
constexpr int NT    = 256;
constexpr int ROWS  = 128;   // 4 waves x 32 rows

typedef float    f32x4  __attribute__((ext_vector_type(4)));
typedef float    f32x16 __attribute__((ext_vector_type(16)));
typedef _Float16 f16x8  __attribute__((ext_vector_type(8)));
typedef unsigned u32x4  __attribute__((ext_vector_type(4)));

static constexpr float LOG2E  = 1.4426950408889634f;
static constexpr float RCP256 = 0.00390625f;

static __device__ __forceinline__ unsigned pkrtz(float a, float b) {
    return __builtin_bit_cast(unsigned, __builtin_amdgcn_cvt_pkrtz(a, b));
}
#define PK8(a0,a1,a2,a3,a4,a5,a6,a7) \
    __builtin_bit_cast(f16x8, (u32x4){pkrtz(a0,a1), pkrtz(a2,a3), \
                                      pkrtz(a4,a5), pkrtz(a6,a7)})

#define MFMA32(A, B, C) __builtin_amdgcn_mfma_f32_32x32x16_f16((A), (B), (C), 0, 0, 0)

// W chunk base (halfs): chunk (g, M, s) = ((g*2+M)*4+s) * 512
#define WOFF(g, M, s) (((((g) * 2) + (M)) * 4 + (s)) * 512)
// aug chunk base: (g*2+M)*512
#define AOFF(g, M) ((((g) * 2) + (M)) * 512)

#define LD_W(g, M, s) (*(const f16x8*)&sWhi[WOFF(g, M, s) + Lx8])
#define LD_AUG(g, M)  (*(const f16x8*)&sAug[AOFF(g, M) + Lx8])

// F[4q..4q+3] = sigmoid on quad q of C (exp2 domain); quad rcp
#define SIGQ(F, C, q) { \
    const float e0_ = __builtin_amdgcn_exp2f(C[4*(q)+0]); \
    const float e1_ = __builtin_amdgcn_exp2f(C[4*(q)+1]); \
    const float e2_ = __builtin_amdgcn_exp2f(C[4*(q)+2]); \
    const float e3_ = __builtin_amdgcn_exp2f(C[4*(q)+3]); \
    const float d0_ = 1.0f + e0_, d1_ = 1.0f + e1_; \
    const float d2_ = 1.0f + e2_, d3_ = 1.0f + e3_; \
    const float d01_ = d0_ * d1_, d23_ = d2_ * d3_; \
    const float ii_  = __builtin_amdgcn_rcpf(d01_ * d23_); \
    const float i01_ = ii_ * d23_, i23_ = ii_ * d01_; \
    F[4*(q)+0] = d1_ * i01_; F[4*(q)+1] = d0_ * i01_; \
    F[4*(q)+2] = d3_ * i23_; F[4*(q)+3] = d2_ * i23_; }

// S quad q: S = S + F*(tanh - S); tanh = 1 - 2/(1+exp2(C)); quad rcp
#define UPDQ(S, F, C, q) { \
    const float e0_ = __builtin_amdgcn_exp2f(C[4*(q)+0]); \
    const float e1_ = __builtin_amdgcn_exp2f(C[4*(q)+1]); \
    const float e2_ = __builtin_amdgcn_exp2f(C[4*(q)+2]); \
    const float e3_ = __builtin_amdgcn_exp2f(C[4*(q)+3]); \
    const float d0_ = 1.0f + e0_, d1_ = 1.0f + e1_; \
    const float d2_ = 1.0f + e2_, d3_ = 1.0f + e3_; \
    const float d01_ = d0_ * d1_, d23_ = d2_ * d3_; \
    const float ii_  = __builtin_amdgcn_rcpf(d01_ * d23_); \
    const float j01_ = -2.0f * (ii_ * d23_), j23_ = -2.0f * (ii_ * d01_); \
    const float t0_ = fmaf(d1_, j01_, 1.0f); \
    const float t1_ = fmaf(d0_, j01_, 1.0f); \
    const float t2_ = fmaf(d3_, j23_, 1.0f); \
    const float t3_ = fmaf(d2_, j23_, 1.0f); \
    S[4*(q)+0] = fmaf(F[4*(q)+0], t0_ - S[4*(q)+0], S[4*(q)+0]); \
    S[4*(q)+1] = fmaf(F[4*(q)+1], t1_ - S[4*(q)+1], S[4*(q)+1]); \
    S[4*(q)+2] = fmaf(F[4*(q)+2], t2_ - S[4*(q)+2], S[4*(q)+2]); \
    S[4*(q)+3] = fmaf(F[4*(q)+3], t3_ - S[4*(q)+3], S[4*(q)+3]); }

// forget gate, unit-tile M: aug + 4 ksteps + sigmoid into F
#define FGATE(M, F) { \
    f32x16 cf_ = MFMA32(LD_AUG(0, M), augB, z16); \
    cf_ = MFMA32(LD_W(0, M, 0), BS0, cf_); \
    cf_ = MFMA32(LD_W(0, M, 1), BS1, cf_); \
    cf_ = MFMA32(LD_W(0, M, 2), BS2, cf_); \
    cf_ = MFMA32(LD_W(0, M, 3), BS3, cf_); \
    SIGQ(F, cf_, 0) SIGQ(F, cf_, 1) SIGQ(F, cf_, 2) SIGQ(F, cf_, 3) }

// B-frag of G = F.*S for kstep s (f32 products, pkrtz)
#define BGS(s) PK8(F0[4*(s)+0]*S0[4*(s)+0], F0[4*(s)+1]*S0[4*(s)+1], \
                   F0[4*(s)+2]*S0[4*(s)+2], F0[4*(s)+3]*S0[4*(s)+3], \
                   F1[4*(s)+0]*S1[4*(s)+0], F1[4*(s)+1]*S1[4*(s)+1], \
                   F1[4*(s)+2]*S1[4*(s)+2], F1[4*(s)+3]*S1[4*(s)+3])

__global__ __launch_bounds__(NT, 2) void mgu_fwd(
    const float* __restrict__ x,    // [B, TAU]
    const float* __restrict__ h0,   // [B, HID]
    const float* __restrict__ Wf,   // [HID, FAN]
    const float* __restrict__ bfv,  // [HID]
    const float* __restrict__ Wc,   // [HID, FAN]
    const float* __restrict__ bcv,  // [HID]
    const float* __restrict__ Wo,   // [1, HID]
    const float* __restrict__ bov,  // [1]
    float* __restrict__ out)        // [B, 1]
{
    __shared__ _Float16 sWhi[8192];   // 16 W chunks x 512 halfs (16 KB)
    __shared__ _Float16 sAug[2048];   // 4 aug chunks x 512 (4 KB)
    __shared__ float sX[ROWS * TAU];  // 10 KB
    __shared__ float sWo[HID];

    const int tid = threadIdx.x;
    const long rb0 = (long)blockIdx.x * ROWS;

    // ---- one-time: W -> sigma-ordered A-fragments (exp2-domain scale)
    for (int idx = tid; idx < 8192; idx += NT) {
        const int c = idx >> 9, p = idx & 511;
        const int Lr = p >> 3, i = p & 7;
        const int g = c >> 3, M = (c >> 2) & 1, s = c & 3;
        const int m = 32 * M + (Lr & 31);
        const int u = (i & 3) + 4 * (Lr >> 5) + 8 * s + 32 * (i >> 2); // sigma
        const float* Wg = g ? Wc : Wf;
        const float sc = g ? (2.0f * LOG2E) : (-LOG2E);
        sWhi[idx] = (_Float16)(sc * Wg[m * FAN + 1 + u]);
    }
    // ---- one-time: aug A-frags (bias + x-column, full split), h=1 slots zero
    for (int idx = tid; idx < 2048; idx += NT) {
        const int c = idx >> 9, p = idx & 511;
        const int Lr = p >> 3, i = p & 7;
        const int g = c >> 1, M = c & 1;
        _Float16 v = (_Float16)0.0f;
        if (Lr < 32 && i < 5) {
            const float* Wg = g ? Wc : Wf;
            const float* bg = g ? bcv : bfv;
            const float sc = g ? (2.0f * LOG2E) : (-LOG2E);
            const int m = 32 * M + Lr;
            const float fx = sc * Wg[m * FAN];
            const float fb = sc * bg[m];
            const float fxh = (float)(_Float16)fx;
            const float fbh = (float)(_Float16)fb;
            v = (i == 0) ? (_Float16)fx
              : (i == 1) ? (_Float16)((fx - fxh) * 256.0f)
              : (i == 2) ? (_Float16)fx
              : (i == 3) ? (_Float16)fb
              :            (_Float16)((fb - fbh) * 256.0f);
        }
        sAug[idx] = v;
    }
    for (int i2 = tid; i2 < ROWS * TAU; i2 += NT) sX[i2] = x[rb0 * TAU + i2];
    if (tid < HID) sWo[tid] = Wo[tid];
    __syncthreads();

    const int w = tid >> 6, L = tid & 63;
    const int hh = L >> 5;            // lane half (k-group / unit-offset 4h)
    const int n  = L & 31;            // row within wave
    const int lrow = w * 32 + n;
    const long gr = rb0 + lrow;
    const int Lx8 = L * 8;

    const f32x16 z16 = {0.f,0.f,0.f,0.f,0.f,0.f,0.f,0.f,
                        0.f,0.f,0.f,0.f,0.f,0.f,0.f,0.f};

    // ---- state: S_M[reg=4q+e] = H[32M + 8q + 4hh + e][row]
    f32x16 S0, S1;
    {
        const float* hp = h0 + gr * HID + 4 * hh;
#define LDQ(SM, M, q) { const f32x4 v_ = *(const f32x4*)(hp + 32*(M) + 8*(q)); \
        SM[4*(q)+0]=v_[0]; SM[4*(q)+1]=v_[1]; SM[4*(q)+2]=v_[2]; SM[4*(q)+3]=v_[3]; }
        LDQ(S0,0,0) LDQ(S0,0,1) LDQ(S0,0,2) LDQ(S0,0,3)
        LDQ(S1,1,0) LDQ(S1,1,1) LDQ(S1,1,2) LDQ(S1,1,3)
#undef LDQ
    }

    #pragma unroll 1
    for (int t = 0; t < TAU; ++t) {
        // ---- aug B-frag: h=0 lanes [xh, xh*2^-8, xl, 1, 2^-8, 0,0,0]; h=1 zero
        const float xt = sX[lrow * TAU + t];
        f16x8 augB;
        {
            const _Float16 xh = (_Float16)xt;
            const float xhf = (float)xh;
            unsigned d0 = pkrtz(xhf, xhf * RCP256);
            unsigned d1 = pkrtz(xt - xhf, 1.0f);
            unsigned d2 = pkrtz(RCP256, 0.0f);
            if (hh != 0) { d0 = 0; d1 = 0; d2 = 0; }
            augB = __builtin_bit_cast(f16x8, (u32x4){d0, d1, d2, 0u});
        }

        // ---- B-frags of S: slot i of kstep s = S[M=i>>2][4s + (i&3)]
        const f16x8 BS0 = PK8(S0[ 0],S0[ 1],S0[ 2],S0[ 3], S1[ 0],S1[ 1],S1[ 2],S1[ 3]);
        const f16x8 BS1 = PK8(S0[ 4],S0[ 5],S0[ 6],S0[ 7], S1[ 4],S1[ 5],S1[ 6],S1[ 7]);
        const f16x8 BS2 = PK8(S0[ 8],S0[ 9],S0[10],S0[11], S1[ 8],S1[ 9],S1[10],S1[11]);
        const f16x8 BS3 = PK8(S0[12],S0[13],S0[14],S0[15], S1[12],S1[13],S1[14],S1[15]);

        // ---- forget gate (both unit-tiles)
        f32x16 F0, F1;
        FGATE(0, F0)
        FGATE(1, F1)

        // ---- candidate gate: aug, then per-kstep BG -> 2 MFMAs
        f32x16 Cc0 = MFMA32(LD_AUG(1, 0), augB, z16);
        f32x16 Cc1 = MFMA32(LD_AUG(1, 1), augB, z16);
        __builtin_amdgcn_s_setprio(1);
        { const f16x8 bg_ = BGS(0);
          Cc0 = MFMA32(LD_W(1, 0, 0), bg_, Cc0); Cc1 = MFMA32(LD_W(1, 1, 0), bg_, Cc1); }
        { const f16x8 bg_ = BGS(1);
          Cc0 = MFMA32(LD_W(1, 0, 1), bg_, Cc0); Cc1 = MFMA32(LD_W(1, 1, 1), bg_, Cc1); }
        { const f16x8 bg_ = BGS(2);
          Cc0 = MFMA32(LD_W(1, 0, 2), bg_, Cc0); Cc1 = MFMA32(LD_W(1, 1, 2), bg_, Cc1); }
        { const f16x8 bg_ = BGS(3);
          Cc0 = MFMA32(LD_W(1, 0, 3), bg_, Cc0); Cc1 = MFMA32(LD_W(1, 1, 3), bg_, Cc1); }
        __builtin_amdgcn_s_setprio(0);

        // ---- update: S = S + F * (tanh - S)
        UPDQ(S0, F0, Cc0, 0) UPDQ(S0, F0, Cc0, 1)
        UPDQ(S0, F0, Cc0, 2) UPDQ(S0, F0, Cc0, 3)
        UPDQ(S1, F1, Cc1, 0) UPDQ(S1, F1, Cc1, 1)
        UPDQ(S1, F1, Cc1, 2) UPDQ(S1, F1, Cc1, 3)
    }

    // ---- output: out[row] = bo + Wo . H[row]; units split across lane pairs
    float acc = 0.0f;
#define WOACC(SM, M, q) { \
    const f32x4 wv_ = *(const f32x4*)&sWo[32*(M) + 8*(q) + 4*hh]; \
    acc = fmaf(wv_[0], SM[4*(q)+0], acc); acc = fmaf(wv_[1], SM[4*(q)+1], acc); \
    acc = fmaf(wv_[2], SM[4*(q)+2], acc); acc = fmaf(wv_[3], SM[4*(q)+3], acc); }
    WOACC(S0, 0, 0) WOACC(S0, 0, 1) WOACC(S0, 0, 2) WOACC(S0, 0, 3)
    WOACC(S1, 1, 0) WOACC(S1, 1, 1) WOACC(S1, 1, 2) WOACC(S1, 1, 3)
#undef WOACC
    acc += __shfl_xor(acc, 32, 64);   // combine the two unit-halves of this row
    if (L < 32) out[gr] = acc + bov[0];
}

extern "C" void kernel_launch(void* const* d_in, const int* in_sizes, int n_in,
                              void* d_out, int out_size, void* d_ws, size_t ws_size,
                              hipStream_t stream) {
    const float* x  = (const float*)d_in[0];
    const float* h0 = (const float*)d_in[1];
    const float* Wf = (const float*)d_in[2];
    const float* bf = (const float*)d_in[3];
    const float* Wc = (const float*)d_in[4];
    const float* bc = (const float*)d_in[5];
    const float* Wo = (const float*)d_in[6];
    const float* bo = (const float*)d_in[7];
    float* out = (float*)d_out;

    hipLaunchKernelGGL(mgu_fwd, dim3(BATCH / ROWS), dim3(NT), 0, stream,
                       x, h0, Wf, bf, Wc, bc, Wo, bo, out);
}